// Round 11
// baseline (143.925 us; speedup 1.0000x reference)
//
#include <hip/hip_runtime.h>
#include <math.h>

#define NN 768
#define DD 64
#define WPB 4                        // waves per block in k_main (256 thr, known-good codegen)
#define HALVES 3                     // j-range split: 3 blocks per row
#define JW (NN / HALVES)             // j per block = 256 -> 64 j per wave
#define NSUB 4                       // 16-j MFMA sub-tiles per wave
#define RSTRIDE 34                   // LDS r-bounce row stride in dwords (pad 2)
#define PREBLKS 18                   // k_prepack: frag/pack blocks before row blocks
#define PSTRIDE 68                   // partial row stride in floats (A[64], M, L, pad)
#define LOG2E 1.4426950408889634f    // all softmax/sigmoid logits carried in base-2 domain

typedef _Float16 half8 __attribute__((ext_vector_type(8)));
typedef float    f32x4 __attribute__((ext_vector_type(4)));
typedef __fp16   p2f   __attribute__((ext_vector_type(2)));

union FragU { uint4 u4; unsigned int u[4]; half8 h; };
union PkU   { unsigned int u; p2f p; };

__device__ __forceinline__ unsigned int pk2(float a, float b) {
    PkU t; t.p = __builtin_amdgcn_cvt_pkrtz(a, b); return t.u;
}
__device__ __forceinline__ float lane_bcast(float v, int src) {
    return __int_as_float(__builtin_amdgcn_readlane(__float_as_int(v), src));
}
__device__ __forceinline__ float rfl(float v) {   // force SGPR residency
    return __int_as_float(__builtin_amdgcn_readfirstlane(__float_as_int(v)));
}
__device__ __forceinline__ float fexp2(float x) { // raw v_exp (base-2), no log2e mul
    float r; asm("v_exp_f32 %0, %1" : "=v"(r) : "v"(x)); return r;
}
__device__ __forceinline__ float frcp(float x) {  // raw v_rcp
    float r; asm("v_rcp_f32 %0, %1" : "=v"(r) : "v"(x)); return r;
}
__device__ __forceinline__ f32x4 mfma16(FragU a, FragU b, f32x4 c) {
    return __builtin_amdgcn_mfma_f32_16x16x32_f16(a.h, b.h, c, 0, 0, 0);
}

// ---------- Kernel 0: pack fragments / hf16 / moments (blk<18) + per-row pre (blk>=18)
__global__ __launch_bounds__(256) void k_prepack(
    const float* __restrict__ hs, const float* __restrict__ ng_w,
    const float* __restrict__ ng_b, const float* __restrict__ war_w,
    const float* __restrict__ war_b,
    const float* __restrict__ rel_w, const float* __restrict__ rel_b,
    const float* __restrict__ rel_lw, const float* __restrict__ rel_lb,
    float* __restrict__ sbase, float* __restrict__ warb, float* __restrict__ war3,
    unsigned int* __restrict__ hf16,
    unsigned int* __restrict__ afragS, unsigned int* __restrict__ afragR,
    float* __restrict__ mom)
{
    const int t = threadIdx.x, blk = blockIdx.x;
    const int lane = t & 63, q = t >> 6, g = lane >> 4, c16 = lane & 15;

    if (blk >= PREBLKS) {
        // per-row: sbase = h@W2 + ng_b ; warb/war3 pre-scaled by log2e (softmax
        // runs in base-2 domain; exp2(log2e*x) == exp(x) exactly).
        const int row = (blk - PREBLKS) * 4 + q;
        const float hv = hs[row * DD + lane];
        float a2 = ng_b[lane];
        #pragma unroll 8
        for (int k = 0; k < DD; ++k)
            a2 = fmaf(lane_bcast(hv, k), ng_w[(DD + k) * DD + lane], a2);
        sbase[row * DD + lane] = a2;
        float t2 = hv * war_w[DD + lane];
        float t3 = hv * war_w[2 * DD + lane];
        #pragma unroll
        for (int o = 32; o; o >>= 1) { t2 += __shfl_xor(t2, o); t3 += __shfl_xor(t3, o); }
        if (lane == 0) {
            warb[row] = (t2 + war_b[0]) * LOG2E;
            war3[row] = t3 * LOG2E;
        }
        return;
    }

    // hf16 pack across blocks 0..17
    for (int idx = blk * 256 + t; idx < NN * 32; idx += PREBLKS * 256) {
        const int row = idx >> 5, c = idx & 31;
        hf16[idx] = pk2(hs[row * DD + 2 * c], hs[row * DD + 2 * c + 1]);
    }

    if (blk < 16) {
        // GEMM2 S A-fragments: A[m=dout][k], frag id = b*4+c
        const int b = blk >> 2, c = blk & 3;
        const int dout = 16 * b + c16;
        const int k0 = 32 * c + g * 8 + 2 * q;
        const int r0 = (k0 < 64) ? k0 : (k0 + 64);   // W1 rows 0..63 ; W3 rows 128..191
        afragS[(blk * 64 + lane) * 4 + q] =
            pk2(ng_w[r0 * DD + dout], ng_w[(r0 + 1) * DD + dout]);
    } else if (blk == 16) {
        // GEMM1 A-fragments, split-precision:
        //   k0..5: wh (pairs xh) ; k8..13: wh (pairs xl) ; k16..21: wl (pairs xh)
        const int b = q;                      // m-block
        const int d = 16 * b + c16;
        const float rlwd = rel_lw[d], rlbd = rel_lb[d];
        const float c0 = rel_w[d] * rlwd;
        const float c1 = rel_w[DD + d] * rlwd;
        const float c2 = rel_w[2 * DD + d] * rlwd;
        const float c3 = rel_b[d] * rlwd;
        PkU h01, h23, h45;
        h01.p = __builtin_amdgcn_cvt_pkrtz(c0, c1);
        h23.p = __builtin_amdgcn_cvt_pkrtz(c2, c3);
        h45.p = __builtin_amdgcn_cvt_pkrtz(rlwd, rlbd);
        const unsigned l01 = pk2(c0 - (float)h01.p[0], c1 - (float)h01.p[1]);
        const unsigned l23 = pk2(c2 - (float)h23.p[0], c3 - (float)h23.p[1]);
        const unsigned l45 = pk2(rlwd - (float)h45.p[0], rlbd - (float)h45.p[1]);
        const unsigned int base = (b * 64 + lane) * 4;
        unsigned v0, v1, v2;
        if (g == 0 || g == 1)      { v0 = h01.u; v1 = h23.u; v2 = h45.u; }
        else if (g == 2)           { v0 = l01;   v1 = l23;   v2 = l45;   }
        else                       { v0 = 0u;    v1 = 0u;    v2 = 0u;    }
        afragR[base + 0] = v0;
        afragR[base + 1] = v1;
        afragR[base + 2] = v2;
        afragR[base + 3] = 0u;
    } else { // blk == 17: rel-LN moment matrix
        if (t < 64) {
            const float x0 = rel_w[t], x1 = rel_w[DD + t], x2 = rel_w[2 * DD + t];
            const float x3 = rel_b[t];
            float v[14] = {x0, x1, x2, x3,
                           x0 * x0, x1 * x1, x2 * x2, x3 * x3,
                           x0 * x1, x0 * x2, x0 * x3, x1 * x2, x1 * x3, x2 * x3};
            #pragma unroll
            for (int qq = 0; qq < 14; ++qq) {
                float s = v[qq];
                #pragma unroll
                for (int o = 32; o; o >>= 1) s += __shfl_xor(s, o);
                if (t == 0) mom[qq] = s * (1.f / 64.f);
            }
        }
    }
}

// ---------- Kernel 1: one (row i, j-third h) per block; each wave owns 64 j.
//            2-stage software pipeline over sub-tiles: phase A (loads, GEMM1,
//            wd partials, LDS bounce, hv loads) of tile s+1 overlaps phase B
//            (wd shuffles, GEMM2, LN, softmax, gate) of tile s. Same-wave DS
//            ops are in-order, so the single smr buffer is hazard-free.
__global__ __launch_bounds__(64 * WPB) void k_main(
    const float* __restrict__ corr, const int* __restrict__ nei,
    const float* __restrict__ hs, const float* __restrict__ av,
    const float* __restrict__ ng_lw, const float* __restrict__ ng_lb,
    const float* __restrict__ war_w,
    const float* __restrict__ sbase, const float* __restrict__ warb,
    const float* __restrict__ war3,
    const unsigned int* __restrict__ afragS, const unsigned int* __restrict__ afragR,
    const unsigned int* __restrict__ hf16, const float* __restrict__ mom,
    float* __restrict__ part)
{
    const int h = blockIdx.x;        // 0..HALVES-1
    const int i = blockIdx.y;        // 0..NN-1
    const int tid = threadIdx.x;
    const int lane = tid & 63, wave = tid >> 6;
    const int g = lane >> 4, c16 = lane & 15;

    __shared__ uint4 sm_aS[16 * 64];                 // 16 KB: GEMM2 A-fragments
    __shared__ __align__(16) float sm_cst[4 * DD];   // sb | war16*log2e | lw*log2e | lb*log2e
    __shared__ uint4 sm_b1h[WPB * 64];               // 4 KB: B1 hi words (SoA)
    __shared__ uint4 sm_b1l[WPB * 64];               // 4 KB: B1 lo words (SoA)
    __shared__ unsigned int smr[WPB * 16 * RSTRIDE];
    __shared__ float sm_red[WPB][DD];
    __shared__ float sm_m[WPB], sm_l[WPB];

    // ---- stage loop-invariant operands into LDS ----
    for (int f = tid; f < 16 * 64; f += 64 * WPB)
        sm_aS[f] = ((const uint4*)afragS)[f];
    {
        const int a = tid >> 6, d = tid & 63;
        float v;
        if (a == 0)      v = sbase[i * DD + d];
        else if (a == 1) v = war_w[d] * LOG2E;
        else if (a == 2) v = ng_lw[d] * LOG2E;
        else             v = ng_lb[d] * LOG2E;
        sm_cst[a * DD + d] = v;
    }

    // GEMM1 A-fragments stay in registers (small, hot)
    FragU aR[4];
    #pragma unroll
    for (int b = 0; b < 4; ++b) aR[b].u4 = ((const uint4*)afragR)[b * 64 + lane];

    // wave-uniform scalars -> SGPR
    const float m0 = rfl(mom[0]), m1 = rfl(mom[1]), m2 = rfl(mom[2]), m3 = rfl(mom[3]);
    const float M00 = rfl(mom[4]), M11 = rfl(mom[5]), M22 = rfl(mom[6]), M33 = rfl(mom[7]);
    const float M01 = rfl(mom[8]), M02 = rfl(mom[9]), M03 = rfl(mom[10]);
    const float M12 = rfl(mom[11]), M13 = rfl(mom[12]), M23 = rfl(mom[13]);
    const float warbase = rfl(warb[i]);              // already *log2e

    unsigned int* wrbase = smr + (wave * 16 + c16) * RSTRIDE;

    __syncthreads();

    // ---------- front-end: ONE j per lane (no g-redundancy) ----------
    const int jwbase = h * JW + wave * 64;
    {
        const int j = jwbase + lane;
        const float2 cc = ((const float2*)corr)[i * NN + j];
        const float2 vv = ((const float2*)av)[j];
        const float cx = cc.x, cy = cc.y;
        const float judge = vv.x * vv.x + vv.y * vv.y;
        const float dotv = fmaf(vv.x, cx, vv.y * cy);
        const float cn = cx * cx + cy * cy;
        float angle = __fdividef(dotv, sqrtf(judge * cn) + 1e-10f);
        if (judge == 0.f) angle = -1.f;

        // analytic rel-LN stats (quadratic form)
        const float u = fmaf(cx, m0, fmaf(cy, m1, fmaf(angle, m2, m3)));
        float e2 = M33;
        e2 = fmaf(cx * cx, M00, e2);
        e2 = fmaf(cy * cy, M11, e2);
        e2 = fmaf(angle * angle, M22, e2);
        e2 = fmaf(2.f * cx, fmaf(cy, M01, fmaf(angle, M02, M03)), e2);
        e2 = fmaf(2.f * cy, fmaf(angle, M12, M13), e2);
        e2 = fmaf(2.f * angle, M23, e2);
        const float vare = (e2 - u * u) + 1e-5f;
        const float inv = rsqrtf(vare);

        // B operand with inv FOLDED IN: x' = (cx,cy,angle,1,-u,sig)*inv
        // (sig*inv == 1 exactly). Then r = relu(P) directly, no post-scale.
        const float xc0 = cx * inv, xc1 = cy * inv, xc2 = angle * inv;
        const float xc3 = inv, xc4 = -u * inv;
        PkU s01, s23, s45;
        s01.p = __builtin_amdgcn_cvt_pkrtz(xc0, xc1);
        s23.p = __builtin_amdgcn_cvt_pkrtz(xc2, xc3);
        s45.p = __builtin_amdgcn_cvt_pkrtz(xc4, 1.f);
        const unsigned l0 = pk2(xc0 - (float)s01.p[0], xc1 - (float)s01.p[1]);
        const unsigned l1 = pk2(xc2 - (float)s23.p[0], xc3 - (float)s23.p[1]);
        const unsigned l2 = pk2(xc4 - (float)s45.p[0], 0.f);

        sm_b1h[wave * 64 + lane] = make_uint4(s01.u, s23.u, s45.u, 0u);
        sm_b1l[wave * 64 + lane] = make_uint4(l0, l1, l2, 0u);
    }

    // ---- phase A: front half of one sub-tile (no cross-lane ops) ----
    auto phaseA = [&](int tt, const float* cst,
                      int& NV, float& W3, FragU& BX2, FragU& BX3,
                      FragU& BX0, FragU& BX1,
                      f32x4& HV0, f32x4& HV1, f32x4& HV2, f32x4& HV3,
                      float& WD) {
        const int jj = jwbase + 16 * tt + c16;
        NV = nei[i * NN + jj];
        W3 = war3[jj];                         // already *log2e
        BX2.u4 = *(const uint4*)(hf16 + jj * 32 + 4 * g);
        BX3.u4 = *(const uint4*)(hf16 + jj * 32 + 16 + 4 * g);

        FragU b1;
        {
            const int bi = wave * 64 + 16 * tt + c16;
            const uint4 w = (g == 1) ? sm_b1l[bi] : sm_b1h[bi];
            b1.u[0] = (g == 3) ? 0u : w.x;
            b1.u[1] = (g == 3) ? 0u : w.y;
            b1.u[2] = (g == 3) ? 0u : w.z;
            b1.u[3] = 0u;
        }

        const f32x4 Z = {0.f, 0.f, 0.f, 0.f};
        float wdp[4];                          // static-indexed (unrolled)
        #pragma unroll
        for (int b = 0; b < 4; ++b) {
            const f32x4 P = mfma16(aR[b], b1, Z);
            const f32x4 wv = *(const f32x4*)(cst + 1 * DD + 16 * b + 4 * g);
            const float r0f = fmaxf(P[0], 0.f);
            const float r1f = fmaxf(P[1], 0.f);
            const float r2f = fmaxf(P[2], 0.f);
            const float r3f = fmaxf(P[3], 0.f);
            float wp = r0f * wv[0];
            wp = fmaf(r1f, wv[1], wp);
            wp = fmaf(r2f, wv[2], wp);
            wp = fmaf(r3f, wv[3], wp);
            wdp[b] = wp;
            uint2 wvv;
            wvv.x = pk2(r0f, r1f);
            wvv.y = pk2(r2f, r3f);
            *(uint2*)(wrbase + 8 * b + 2 * g) = wvv;   // d2 = 8b+2g
        }
        WD = (wdp[0] + wdp[1]) + (wdp[2] + wdp[3]);

        // bounce read-back (same-wave DS in-order: safe, single buffer)
        {
            const uint2 lo0 = *(const uint2*)(wrbase + 4 * g);
            const uint2 hi0 = *(const uint2*)(wrbase + 4 * g + 2);
            BX0.u[0] = lo0.x; BX0.u[1] = lo0.y; BX0.u[2] = hi0.x; BX0.u[3] = hi0.y;
            const uint2 lo1 = *(const uint2*)(wrbase + 16 + 4 * g);
            const uint2 hi1 = *(const uint2*)(wrbase + 16 + 4 * g + 2);
            BX1.u[0] = lo1.x; BX1.u[1] = lo1.y; BX1.u[2] = hi1.x; BX1.u[3] = hi1.y;
        }

        HV0 = *(const f32x4*)(hs + jj * DD +  0 + 4 * g);
        HV1 = *(const f32x4*)(hs + jj * DD + 16 + 4 * g);
        HV2 = *(const f32x4*)(hs + jj * DD + 32 + 4 * g);
        HV3 = *(const f32x4*)(hs + jj * DD + 48 + 4 * g);
    };

    float acc[16];
    #pragma unroll
    for (int x = 0; x < 16; ++x) acc[x] = 0.f;
    float mrun = -INFINITY, lrun = 0.f;

    // pipeline prologue: A(0) into cur state
    int   nv_c;  float w3_c, wd_c;
    FragU bx2_c, bx3_c, bx0_c, bx1_c;
    f32x4 hv0_c, hv1_c, hv2_c, hv3_c;
    phaseA(0, sm_cst, nv_c, w3_c, bx2_c, bx3_c, bx0_c, bx1_c,
           hv0_c, hv1_c, hv2_c, hv3_c, wd_c);

    unsigned zofs = 0;   // opaque 0: blocks LICM from hoisting LDS reads to regs

    #pragma unroll 1
    for (int s = 0; s < NSUB; ++s) {
        asm volatile("" : "+v"(zofs));
        const uint4* aSp = sm_aS + zofs;
        const float* cst = sm_cst + zofs;

        // ---- A(s+1): independent of B(s); fills B's stall slots ----
        const int tn = (s + 1 < NSUB) ? s + 1 : s;   // last iter: harmless recompute
        int   nv_n;  float w3_n, wd_n;
        FragU bx2_n, bx3_n, bx0_n, bx1_n;
        f32x4 hv0_n, hv1_n, hv2_n, hv3_n;
        phaseA(tn, cst, nv_n, w3_n, bx2_n, bx3_n, bx0_n, bx1_n,
               hv0_n, hv1_n, hv2_n, hv3_n, wd_n);

        // ---- B(s): back half with cur state ----
        float wd = wd_c;
        wd += __shfl_xor(wd, 16);
        wd += __shfl_xor(wd, 32);     // full r@war[0:64] (scaled) for this lane's jj

        // GEMM2: S[dout][j], C-init = sbase (LDS); A-fragments from LDS.
        f32x4 S[4];
        #pragma unroll
        for (int b = 0; b < 4; ++b) {
            f32x4 cinit = *(const f32x4*)(cst + 0 * DD + 16 * b + 4 * g);
            FragU a2f, a3f, a0f, a1f;
            a2f.u4 = aSp[(b * 4 + 2) * 64 + lane];
            a3f.u4 = aSp[(b * 4 + 3) * 64 + lane];
            a0f.u4 = aSp[(b * 4 + 0) * 64 + lane];
            a1f.u4 = aSp[(b * 4 + 1) * 64 + lane];
            cinit = mfma16(a2f, bx2_c, cinit);
            cinit = mfma16(a3f, bx3_c, cinit);
            cinit = mfma16(a0f, bx0_c, cinit);
            cinit = mfma16(a1f, bx1_c, cinit);
            S[b] = cinit;
        }

        // LayerNorm stats over dout (2 independent chains + xor16/32)
        float s1a = 0.f, s1b = 0.f, s2a = 0.f, s2b = 0.f;
        #pragma unroll
        for (int x = 0; x < 8; ++x) {
            const float sv = S[x >> 2][x & 3];
            s1a += sv; s2a = fmaf(sv, sv, s2a);
        }
        #pragma unroll
        for (int x = 8; x < 16; ++x) {
            const float sv = S[x >> 2][x & 3];
            s1b += sv; s2b = fmaf(sv, sv, s2b);
        }
        float s1 = s1a + s1b, s2 = s2a + s2b;
        s1 += __shfl_xor(s1, 16); s1 += __shfl_xor(s1, 32);
        s2 += __shfl_xor(s2, 16); s2 += __shfl_xor(s2, 32);
        const float u2 = s1 * (1.f / 64.f);
        const float var2 = fmaf(s2, 1.f / 64.f, -u2 * u2);
        const float inv2 = rsqrtf(var2 + 1e-5f);

        // attention logit (base-2 domain; relu subsumed by the >0 select)
        const float tt = wd + w3_c + warbase;
        const bool msk = nv_c > 0;
        const float p = (msk && tt > 0.f) ? tt : -10000.f;

        // per-lane online softmax in base-2 (raw v_exp)
        const float mn = fmaxf(mrun, p);
        const float alpha = fexp2(mrun - mn);
        const float e = fexp2(p - mn);
        const float eacc = msk ? e : 0.f;
        lrun = fmaf(lrun, alpha, e);
        mrun = mn;

        // gate + accumulate; LN affine pre-folded AND pre-scaled by log2e:
        // sigmoid(x) = rcp(1 + exp2(-x*log2e)) with the log2e inside ilw/blb.
        #pragma unroll
        for (int b = 0; b < 4; ++b) {
            const f32x4 hvb = (b == 0) ? hv0_c : (b == 1) ? hv1_c
                           : (b == 2) ? hv2_c : hv3_c;
            const f32x4 lw = *(const f32x4*)(cst + 2 * DD + 16 * b + 4 * g);
            const f32x4 lb = *(const f32x4*)(cst + 3 * DD + 16 * b + 4 * g);
            #pragma unroll
            for (int r = 0; r < 4; ++r) {
                const float ilw = inv2 * lw[r];
                const float blb = fmaf(-u2, ilw, lb[r]);
                const float ngv = fmaf(S[b][r], ilw, blb);
                const float gate = frcp(1.f + fexp2(-ngv));
                const float ehv = eacc * hvb[r];
                acc[b * 4 + r] = fmaf(acc[b * 4 + r], alpha, gate * ehv);
            }
        }

        // ---- rotate pipeline state ----
        nv_c = nv_n; w3_c = w3_n; wd_c = wd_n;
        bx2_c = bx2_n; bx3_c = bx3_n; bx0_c = bx0_n; bx1_c = bx1_n;
        hv0_c = hv0_n; hv1_c = hv1_n; hv2_c = hv2_n; hv3_c = hv3_n;
    }

    // softmax-aware merge over the 16 j-classes (bits 0-3); g-duplicates share (m,l)
    #pragma unroll
    for (int o = 1; o <= 8; o <<= 1) {
        const float mo  = __shfl_xor(mrun, o);
        const float lo_ = __shfl_xor(lrun, o);
        const float M   = fmaxf(mrun, mo);
        const float a1  = fexp2(mrun - M);
        const float a2  = fexp2(mo - M);
        lrun = lrun * a1 + lo_ * a2;
        #pragma unroll
        for (int x = 0; x < 16; ++x) {
            const float ao = __shfl_xor(acc[x], o);
            acc[x] = acc[x] * a1 + ao * a2;
        }
        mrun = M;
    }
    if (c16 == 0) {
        #pragma unroll
        for (int b = 0; b < 4; ++b)
            #pragma unroll
            for (int r = 0; r < 4; ++r)
                sm_red[wave][16 * b + g * 4 + r] = acc[b * 4 + r];
        if (lane == 0) { sm_m[wave] = mrun; sm_l[wave] = lrun; }
    }
    __syncthreads();

    // merge the WPB wave partials and emit this third's partial (A, M, L)
    if (tid < DD) {
        float M = sm_m[0];
        #pragma unroll
        for (int w = 1; w < WPB; ++w) M = fmaxf(M, sm_m[w]);
        float L = 0.f, A = 0.f;
        #pragma unroll
        for (int w = 0; w < WPB; ++w) {
            const float f = fexp2(sm_m[w] - M);
            L = fmaf(sm_l[w], f, L);
            A = fmaf(sm_red[w][tid], f, A);
        }
        float* p = part + (i * HALVES + h) * PSTRIDE;
        p[tid] = A;
        if (tid == 0) { p[64] = M; p[65] = L; }
    }
}

// ---------- Kernel 2: merge HALVES partials; fused final MLP + LN + residual --
__global__ __launch_bounds__(64) void k_final(
    const float* __restrict__ hs, const float* __restrict__ part,
    const float* __restrict__ wt_w, const float* __restrict__ wt_b,
    const float* __restrict__ wt_lw, const float* __restrict__ wt_lb,
    float* __restrict__ out)
{
    const int i = blockIdx.x;
    const int tid = threadIdx.x;

    float ms[HALVES], ls[HALVES];
    float M = -INFINITY;
    #pragma unroll
    for (int hh = 0; hh < HALVES; ++hh) {
        const float* p = part + (i * HALVES + hh) * PSTRIDE;
        ms[hh] = p[64]; ls[hh] = p[65];
        M = fmaxf(M, ms[hh]);
    }
    float L = 0.f, A = 0.f;
    #pragma unroll
    for (int hh = 0; hh < HALVES; ++hh) {
        const float f = fexp2(ms[hh] - M);   // M's are in base-2 domain
        L = fmaf(ls[hh], f, L);
        A = fmaf(part[(i * HALVES + hh) * PSTRIDE + tid], f, A);
    }
    const float Hv = A / L;

    float v = wt_b[tid];
    #pragma unroll 8
    for (int k = 0; k < DD; ++k)
        v = fmaf(lane_bcast(Hv, k), wt_w[k * DD + tid], v);
    float t1 = v, t2 = v * v;
    #pragma unroll
    for (int o = 32; o; o >>= 1) { t1 += __shfl_xor(t1, o); t2 += __shfl_xor(t2, o); }
    const float uo = t1 * (1.f / 64.f);
    const float varo = fmaf(t2, 1.f / 64.f, -uo * uo);
    const float invo = rsqrtf(varo + 1e-5f);
    const float ro = fmaf((v - uo) * invo, wt_lw[tid], wt_lb[tid]);
    out[i * DD + tid] = hs[i * DD + tid] + fmaxf(ro, 0.f);
}

extern "C" void kernel_launch(void* const* d_in, const int* in_sizes, int n_in,
                              void* d_out, int out_size, void* d_ws, size_t ws_size,
                              hipStream_t stream) {
    const float* corr   = (const float*)d_in[0];
    const int*   nei    = (const int*)  d_in[1];
    // d_in[2] = nei_num : unused by the reference
    const float* hs     = (const float*)d_in[3];
    const float* av     = (const float*)d_in[4];
    const float* rel_w  = (const float*)d_in[5];
    const float* rel_b  = (const float*)d_in[6];
    const float* rel_lw = (const float*)d_in[7];
    const float* rel_lb = (const float*)d_in[8];
    const float* ng_w   = (const float*)d_in[9];
    const float* ng_b   = (const float*)d_in[10];
    const float* ng_lw  = (const float*)d_in[11];
    const float* ng_lb  = (const float*)d_in[12];
    const float* war_w  = (const float*)d_in[13];
    const float* war_b  = (const float*)d_in[14];
    const float* wt_w   = (const float*)d_in[15];
    const float* wt_b   = (const float*)d_in[16];
    const float* wt_lw  = (const float*)d_in[17];
    const float* wt_lb  = (const float*)d_in[18];
    float* out = (float*)d_out;

    float* ws    = (float*)d_ws;
    float* sbase = ws;                                  // N*D
    float* warb  = sbase + NN * DD;                     // N
    float* war3  = warb + NN;                           // N
    float* mom   = war3 + NN;                           // 14 (+pad to 16)
    unsigned int* hf16   = (unsigned int*)(mom + 16);   // N*32
    unsigned int* afragS = hf16 + NN * 32;              // 16*64*4
    unsigned int* afragR = afragS + 16 * 64 * 4;        // 4*64*4
    float* part  = (float*)(afragR + 4 * 64 * 4);       // N*HALVES*PSTRIDE

    k_prepack<<<PREBLKS + NN / 4, 256, 0, stream>>>(
        hs, ng_w, ng_b, war_w, war_b, rel_w, rel_b, rel_lw, rel_lb,
        sbase, warb, war3, hf16, afragS, afragR, mom);
    k_main<<<dim3(HALVES, NN), 64 * WPB, 0, stream>>>(
        corr, nei, hs, av, ng_lw, ng_lb, war_w, sbase, warb, war3,
        afragS, afragR, hf16, mom, part);
    k_final<<<NN, 64, 0, stream>>>(
        hs, part, wt_w, wt_b, wt_lw, wt_lb, out);
}

// Round 12
// 137.845 us; speedup vs baseline: 1.0441x; 1.0441x over previous
//
#include <hip/hip_runtime.h>
#include <math.h>

#define NN 768
#define DD 64
#define WPB 4                        // waves per block in k_main (256 thr, known-good codegen)
#define HALVES 3                     // j-range split: 3 blocks per row
#define JW (NN / HALVES)             // j per block = 256 -> 64 j per wave
#define NSUB 4                       // 16-j MFMA sub-tiles per wave
#define RSTRIDE 34                   // LDS r-bounce row stride in dwords (pad 2)
#define PREBLKS 18                   // k_prepack: frag/pack blocks before row blocks
#define PSTRIDE 68                   // partial row stride in floats (A[64], M, L, pad)
#define LOG2E 1.4426950408889634f    // all softmax/sigmoid logits carried in base-2 domain

typedef _Float16 half8 __attribute__((ext_vector_type(8)));
typedef float    f32x4 __attribute__((ext_vector_type(4)));
typedef __fp16   p2f   __attribute__((ext_vector_type(2)));

union FragU { uint4 u4; unsigned int u[4]; half8 h; };
union PkU   { unsigned int u; p2f p; };

__device__ __forceinline__ unsigned int pk2(float a, float b) {
    PkU t; t.p = __builtin_amdgcn_cvt_pkrtz(a, b); return t.u;
}
__device__ __forceinline__ float lane_bcast(float v, int src) {
    return __int_as_float(__builtin_amdgcn_readlane(__float_as_int(v), src));
}
__device__ __forceinline__ float rfl(float v) {   // force SGPR residency
    return __int_as_float(__builtin_amdgcn_readfirstlane(__float_as_int(v)));
}
__device__ __forceinline__ float fexp2(float x) { // raw v_exp (base-2), no log2e mul
    float r; asm("v_exp_f32 %0, %1" : "=v"(r) : "v"(x)); return r;
}
__device__ __forceinline__ float frcp(float x) {  // raw v_rcp
    float r; asm("v_rcp_f32 %0, %1" : "=v"(r) : "v"(x)); return r;
}
__device__ __forceinline__ f32x4 mfma16(FragU a, FragU b, f32x4 c) {
    return __builtin_amdgcn_mfma_f32_16x16x32_f16(a.h, b.h, c, 0, 0, 0);
}

// ---------- Kernel 0: pack fragments / hf16 / moments (blk<18) + per-row pre (blk>=18)
__global__ __launch_bounds__(256) void k_prepack(
    const float* __restrict__ hs, const float* __restrict__ ng_w,
    const float* __restrict__ ng_b, const float* __restrict__ war_w,
    const float* __restrict__ war_b,
    const float* __restrict__ rel_w, const float* __restrict__ rel_b,
    const float* __restrict__ rel_lw, const float* __restrict__ rel_lb,
    float* __restrict__ sbase, float* __restrict__ warb, float* __restrict__ war3,
    unsigned int* __restrict__ hf16,
    unsigned int* __restrict__ afragS, unsigned int* __restrict__ afragR,
    float* __restrict__ mom)
{
    const int t = threadIdx.x, blk = blockIdx.x;
    const int lane = t & 63, q = t >> 6, g = lane >> 4, c16 = lane & 15;

    if (blk >= PREBLKS) {
        // per-row: sbase = h@W2 + ng_b ; warb/war3 pre-scaled by log2e (softmax
        // runs in base-2 domain; exp2(log2e*x) == exp(x) exactly).
        const int row = (blk - PREBLKS) * 4 + q;
        const float hv = hs[row * DD + lane];
        float a2 = ng_b[lane];
        #pragma unroll 8
        for (int k = 0; k < DD; ++k)
            a2 = fmaf(lane_bcast(hv, k), ng_w[(DD + k) * DD + lane], a2);
        sbase[row * DD + lane] = a2;
        float t2 = hv * war_w[DD + lane];
        float t3 = hv * war_w[2 * DD + lane];
        #pragma unroll
        for (int o = 32; o; o >>= 1) { t2 += __shfl_xor(t2, o); t3 += __shfl_xor(t3, o); }
        if (lane == 0) {
            warb[row] = (t2 + war_b[0]) * LOG2E;
            war3[row] = t3 * LOG2E;
        }
        return;
    }

    // hf16 pack across blocks 0..17
    for (int idx = blk * 256 + t; idx < NN * 32; idx += PREBLKS * 256) {
        const int row = idx >> 5, c = idx & 31;
        hf16[idx] = pk2(hs[row * DD + 2 * c], hs[row * DD + 2 * c + 1]);
    }

    if (blk < 16) {
        // GEMM2 S A-fragments: A[m=dout][k], frag id = b*4+c
        const int b = blk >> 2, c = blk & 3;
        const int dout = 16 * b + c16;
        const int k0 = 32 * c + g * 8 + 2 * q;
        const int r0 = (k0 < 64) ? k0 : (k0 + 64);   // W1 rows 0..63 ; W3 rows 128..191
        afragS[(blk * 64 + lane) * 4 + q] =
            pk2(ng_w[r0 * DD + dout], ng_w[(r0 + 1) * DD + dout]);
    } else if (blk == 16) {
        // GEMM1 A-fragments, split-precision:
        //   k0..5: wh (pairs xh) ; k8..13: wh (pairs xl) ; k16..21: wl (pairs xh)
        const int b = q;                      // m-block
        const int d = 16 * b + c16;
        const float rlwd = rel_lw[d], rlbd = rel_lb[d];
        const float c0 = rel_w[d] * rlwd;
        const float c1 = rel_w[DD + d] * rlwd;
        const float c2 = rel_w[2 * DD + d] * rlwd;
        const float c3 = rel_b[d] * rlwd;
        PkU h01, h23, h45;
        h01.p = __builtin_amdgcn_cvt_pkrtz(c0, c1);
        h23.p = __builtin_amdgcn_cvt_pkrtz(c2, c3);
        h45.p = __builtin_amdgcn_cvt_pkrtz(rlwd, rlbd);
        const unsigned l01 = pk2(c0 - (float)h01.p[0], c1 - (float)h01.p[1]);
        const unsigned l23 = pk2(c2 - (float)h23.p[0], c3 - (float)h23.p[1]);
        const unsigned l45 = pk2(rlwd - (float)h45.p[0], rlbd - (float)h45.p[1]);
        const unsigned int base = (b * 64 + lane) * 4;
        unsigned v0, v1, v2;
        if (g == 0 || g == 1)      { v0 = h01.u; v1 = h23.u; v2 = h45.u; }
        else if (g == 2)           { v0 = l01;   v1 = l23;   v2 = l45;   }
        else                       { v0 = 0u;    v1 = 0u;    v2 = 0u;    }
        afragR[base + 0] = v0;
        afragR[base + 1] = v1;
        afragR[base + 2] = v2;
        afragR[base + 3] = 0u;
    } else { // blk == 17: rel-LN moment matrix
        if (t < 64) {
            const float x0 = rel_w[t], x1 = rel_w[DD + t], x2 = rel_w[2 * DD + t];
            const float x3 = rel_b[t];
            float v[14] = {x0, x1, x2, x3,
                           x0 * x0, x1 * x1, x2 * x2, x3 * x3,
                           x0 * x1, x0 * x2, x0 * x3, x1 * x2, x1 * x3, x2 * x3};
            #pragma unroll
            for (int qq = 0; qq < 14; ++qq) {
                float s = v[qq];
                #pragma unroll
                for (int o = 32; o; o >>= 1) s += __shfl_xor(s, o);
                if (t == 0) mom[qq] = s * (1.f / 64.f);
            }
        }
    }
}

// ---------- Kernel 1: one (row i, j-third h) per block; each wave owns 64 j.
//            Front-end once per j (1 j/lane); B1 staged in SoA LDS tables.
//            All exp sites are raw v_exp_f32 (base-2 domain; log2e folded
//            into staged constants). Partials -> workspace; k_final merges.
__global__ __launch_bounds__(64 * WPB) void k_main(
    const float* __restrict__ corr, const int* __restrict__ nei,
    const float* __restrict__ hs, const float* __restrict__ av,
    const float* __restrict__ ng_lw, const float* __restrict__ ng_lb,
    const float* __restrict__ war_w,
    const float* __restrict__ sbase, const float* __restrict__ warb,
    const float* __restrict__ war3,
    const unsigned int* __restrict__ afragS, const unsigned int* __restrict__ afragR,
    const unsigned int* __restrict__ hf16, const float* __restrict__ mom,
    float* __restrict__ part)
{
    const int h = blockIdx.x;        // 0..HALVES-1
    const int i = blockIdx.y;        // 0..NN-1
    const int tid = threadIdx.x;
    const int lane = tid & 63, wave = tid >> 6;
    const int g = lane >> 4, c16 = lane & 15;

    __shared__ uint4 sm_aS[16 * 64];                 // 16 KB: GEMM2 A-fragments
    __shared__ __align__(16) float sm_cst[4 * DD];   // sb | war16*log2e | lw*log2e | lb*log2e
    __shared__ uint4 sm_b1h[WPB * 64];               // 4 KB: B1 hi words (SoA)
    __shared__ uint4 sm_b1l[WPB * 64];               // 4 KB: B1 lo words (SoA)
    __shared__ unsigned int smr[WPB * 16 * RSTRIDE];
    __shared__ float sm_red[WPB][DD];
    __shared__ float sm_m[WPB], sm_l[WPB];

    // ---- stage loop-invariant operands into LDS ----
    for (int f = tid; f < 16 * 64; f += 64 * WPB)
        sm_aS[f] = ((const uint4*)afragS)[f];
    {
        const int a = tid >> 6, d = tid & 63;
        float v;
        if (a == 0)      v = sbase[i * DD + d];
        else if (a == 1) v = war_w[d] * LOG2E;
        else if (a == 2) v = ng_lw[d] * LOG2E;
        else             v = ng_lb[d] * LOG2E;
        sm_cst[a * DD + d] = v;
    }

    // GEMM1 A-fragments stay in registers (small, hot)
    FragU aR[4];
    #pragma unroll
    for (int b = 0; b < 4; ++b) aR[b].u4 = ((const uint4*)afragR)[b * 64 + lane];

    // wave-uniform scalars -> SGPR
    const float m0 = rfl(mom[0]), m1 = rfl(mom[1]), m2 = rfl(mom[2]), m3 = rfl(mom[3]);
    const float M00 = rfl(mom[4]), M11 = rfl(mom[5]), M22 = rfl(mom[6]), M33 = rfl(mom[7]);
    const float M01 = rfl(mom[8]), M02 = rfl(mom[9]), M03 = rfl(mom[10]);
    const float M12 = rfl(mom[11]), M13 = rfl(mom[12]), M23 = rfl(mom[13]);
    const float warbase = rfl(warb[i]);              // already *log2e

    unsigned int* wrbase = smr + (wave * 16 + c16) * RSTRIDE;

    __syncthreads();

    // ---------- front-end: ONE j per lane (no g-redundancy) ----------
    const int jwbase = h * JW + wave * 64;
    {
        const int j = jwbase + lane;
        const float2 cc = ((const float2*)corr)[i * NN + j];
        const float2 vv = ((const float2*)av)[j];
        const float cx = cc.x, cy = cc.y;
        const float judge = vv.x * vv.x + vv.y * vv.y;
        const float dotv = fmaf(vv.x, cx, vv.y * cy);
        const float cn = cx * cx + cy * cy;
        float angle = __fdividef(dotv, sqrtf(judge * cn) + 1e-10f);
        if (judge == 0.f) angle = -1.f;

        // analytic rel-LN stats (quadratic form)
        const float u = fmaf(cx, m0, fmaf(cy, m1, fmaf(angle, m2, m3)));
        float e2 = M33;
        e2 = fmaf(cx * cx, M00, e2);
        e2 = fmaf(cy * cy, M11, e2);
        e2 = fmaf(angle * angle, M22, e2);
        e2 = fmaf(2.f * cx, fmaf(cy, M01, fmaf(angle, M02, M03)), e2);
        e2 = fmaf(2.f * cy, fmaf(angle, M12, M13), e2);
        e2 = fmaf(2.f * angle, M23, e2);
        const float vare = (e2 - u * u) + 1e-5f;
        const float inv = rsqrtf(vare);

        // B operand with inv FOLDED IN: x' = (cx,cy,angle,1,-u,sig)*inv
        // (sig*inv == 1 exactly). Then r = relu(P) directly, no post-scale.
        const float xc0 = cx * inv, xc1 = cy * inv, xc2 = angle * inv;
        const float xc3 = inv, xc4 = -u * inv;
        PkU s01, s23, s45;
        s01.p = __builtin_amdgcn_cvt_pkrtz(xc0, xc1);
        s23.p = __builtin_amdgcn_cvt_pkrtz(xc2, xc3);
        s45.p = __builtin_amdgcn_cvt_pkrtz(xc4, 1.f);
        const unsigned l0 = pk2(xc0 - (float)s01.p[0], xc1 - (float)s01.p[1]);
        const unsigned l1 = pk2(xc2 - (float)s23.p[0], xc3 - (float)s23.p[1]);
        const unsigned l2 = pk2(xc4 - (float)s45.p[0], 0.f);

        sm_b1h[wave * 64 + lane] = make_uint4(s01.u, s23.u, s45.u, 0u);
        sm_b1l[wave * 64 + lane] = make_uint4(l0, l1, l2, 0u);
    }

    float acc[16];
    #pragma unroll
    for (int x = 0; x < 16; ++x) acc[x] = 0.f;
    float mrun = -INFINITY, lrun = 0.f;

    unsigned zofs = 0;   // opaque 0: blocks LICM from hoisting LDS reads to regs

    #pragma unroll 1
    for (int s = 0; s < NSUB; ++s) {
        asm volatile("" : "+v"(zofs));
        const uint4* aSp = sm_aS + zofs;
        const float* cst = sm_cst + zofs;

        const int jj = jwbase + 16 * s + c16;
        const int    nv = nei[i * NN + jj];      // g-dup loads: L1 broadcast
        const float  w3 = war3[jj];              // already *log2e
        FragU bx2, bx3;
        bx2.u4 = *(const uint4*)(hf16 + jj * 32 + 4 * g);
        bx3.u4 = *(const uint4*)(hf16 + jj * 32 + 16 + 4 * g);

        // b1 fragment: SoA tables, 16B stride (conflict-free; g0/g2 broadcast)
        FragU b1;
        {
            const int bi = wave * 64 + 16 * s + c16;
            const uint4 w = (g == 1) ? sm_b1l[bi] : sm_b1h[bi];
            b1.u[0] = (g == 3) ? 0u : w.x;
            b1.u[1] = (g == 3) ? 0u : w.y;
            b1.u[2] = (g == 3) ? 0u : w.z;
            b1.u[3] = 0u;
        }

        const f32x4 Z = {0.f, 0.f, 0.f, 0.f};
        // GEMM1 -> r (inv pre-folded); war dot (base-2-scaled) inline; pack to LDS
        float wd = 0.f;
        #pragma unroll
        for (int b = 0; b < 4; ++b) {
            const f32x4 P = mfma16(aR[b], b1, Z);
            const f32x4 wv = *(const f32x4*)(cst + 1 * DD + 16 * b + 4 * g);
            const float r0f = fmaxf(P[0], 0.f);
            const float r1f = fmaxf(P[1], 0.f);
            const float r2f = fmaxf(P[2], 0.f);
            const float r3f = fmaxf(P[3], 0.f);
            wd = fmaf(r0f, wv[0], wd);
            wd = fmaf(r1f, wv[1], wd);
            wd = fmaf(r2f, wv[2], wd);
            wd = fmaf(r3f, wv[3], wd);
            uint2 wvv;
            wvv.x = pk2(r0f, r1f);
            wvv.y = pk2(r2f, r3f);
            *(uint2*)(wrbase + 8 * b + 2 * g) = wvv;   // d2 = 8b+2g, +1
        }

        // issue the LDS reads for GEMM2 chunks 0,1 right behind the writes
        FragU bx0, bx1;
        {
            const uint2 lo0 = *(const uint2*)(wrbase + 4 * g);
            const uint2 hi0 = *(const uint2*)(wrbase + 4 * g + 2);
            bx0.u[0] = lo0.x; bx0.u[1] = lo0.y; bx0.u[2] = hi0.x; bx0.u[3] = hi0.y;
            const uint2 lo1 = *(const uint2*)(wrbase + 16 + 4 * g);
            const uint2 hi1 = *(const uint2*)(wrbase + 16 + 4 * g + 2);
            bx1.u[0] = lo1.x; bx1.u[1] = lo1.y; bx1.u[2] = hi1.x; bx1.u[3] = hi1.y;
        }

        // h_j loads issued mid-sub-tile: consumed at the gate, hidden behind GEMM2+LN
        const f32x4 hv0 = *(const f32x4*)(hs + jj * DD +  0 + 4 * g);
        const f32x4 hv1 = *(const f32x4*)(hs + jj * DD + 16 + 4 * g);
        const f32x4 hv2 = *(const f32x4*)(hs + jj * DD + 32 + 4 * g);
        const f32x4 hv3 = *(const f32x4*)(hs + jj * DD + 48 + 4 * g);

        wd += __shfl_xor(wd, 16);
        wd += __shfl_xor(wd, 32);     // full r@war[0:64] (scaled) for this lane's jj

        // GEMM2: S[dout][j], C-init = sbase (LDS); A-fragments from LDS.
        f32x4 S[4];
        #pragma unroll
        for (int b = 0; b < 4; ++b) {
            f32x4 cinit = *(const f32x4*)(cst + 0 * DD + 16 * b + 4 * g);
            FragU a2f, a3f, a0f, a1f;
            a2f.u4 = aSp[(b * 4 + 2) * 64 + lane];
            a3f.u4 = aSp[(b * 4 + 3) * 64 + lane];
            a0f.u4 = aSp[(b * 4 + 0) * 64 + lane];
            a1f.u4 = aSp[(b * 4 + 1) * 64 + lane];
            cinit = mfma16(a2f, bx2, cinit);
            cinit = mfma16(a3f, bx3, cinit);
            cinit = mfma16(a0f, bx0, cinit);
            cinit = mfma16(a1f, bx1, cinit);
            S[b] = cinit;
        }

        // LayerNorm stats over dout (in-lane 16 + xor16/32)
        float s1 = 0.f, s2 = 0.f;
        #pragma unroll
        for (int x = 0; x < 16; ++x) {
            const float sv = S[x >> 2][x & 3];
            s1 += sv; s2 = fmaf(sv, sv, s2);
        }
        s1 += __shfl_xor(s1, 16); s1 += __shfl_xor(s1, 32);
        s2 += __shfl_xor(s2, 16); s2 += __shfl_xor(s2, 32);
        const float u2 = s1 * (1.f / 64.f);
        const float var2 = fmaf(s2, 1.f / 64.f, -u2 * u2);
        const float inv2 = rsqrtf(var2 + 1e-5f);

        // attention logit (base-2 domain; relu subsumed by the >0 select)
        const float tt = wd + w3 + warbase;
        const bool msk = nv > 0;
        const float p = (msk && tt > 0.f) ? tt : -10000.f;

        // per-lane online softmax in base-2 (raw v_exp)
        const float mn = fmaxf(mrun, p);
        const float alpha = fexp2(mrun - mn);
        const float e = fexp2(p - mn);
        const float eacc = msk ? e : 0.f;
        lrun = fmaf(lrun, alpha, e);
        mrun = mn;

        // gate + accumulate; LN affine pre-folded AND pre-scaled by log2e:
        // sigmoid(x) = rcp(1 + exp2(-x*log2e)) with the log2e inside ilw/blb.
        #pragma unroll
        for (int b = 0; b < 4; ++b) {
            const f32x4 hvb = (b == 0) ? hv0 : (b == 1) ? hv1 : (b == 2) ? hv2 : hv3;
            const f32x4 lw = *(const f32x4*)(cst + 2 * DD + 16 * b + 4 * g);
            const f32x4 lb = *(const f32x4*)(cst + 3 * DD + 16 * b + 4 * g);
            #pragma unroll
            for (int r = 0; r < 4; ++r) {
                const float ilw = inv2 * lw[r];
                const float blb = fmaf(-u2, ilw, lb[r]);
                const float ngv = fmaf(S[b][r], ilw, blb);
                const float gate = frcp(1.f + fexp2(-ngv));
                const float ehv = eacc * hvb[r];
                acc[b * 4 + r] = fmaf(acc[b * 4 + r], alpha, gate * ehv);
            }
        }
    }

    // softmax-aware merge over the 16 j-classes (bits 0-3); g-duplicates share (m,l)
    #pragma unroll
    for (int o = 1; o <= 8; o <<= 1) {
        const float mo  = __shfl_xor(mrun, o);
        const float lo_ = __shfl_xor(lrun, o);
        const float M   = fmaxf(mrun, mo);
        const float a1  = fexp2(mrun - M);
        const float a2  = fexp2(mo - M);
        lrun = lrun * a1 + lo_ * a2;
        #pragma unroll
        for (int x = 0; x < 16; ++x) {
            const float ao = __shfl_xor(acc[x], o);
            acc[x] = acc[x] * a1 + ao * a2;
        }
        mrun = M;
    }
    if (c16 == 0) {
        #pragma unroll
        for (int b = 0; b < 4; ++b)
            #pragma unroll
            for (int r = 0; r < 4; ++r)
                sm_red[wave][16 * b + g * 4 + r] = acc[b * 4 + r];
        if (lane == 0) { sm_m[wave] = mrun; sm_l[wave] = lrun; }
    }
    __syncthreads();

    // merge the WPB wave partials and emit this third's partial (A, M, L)
    if (tid < DD) {
        float M = sm_m[0];
        #pragma unroll
        for (int w = 1; w < WPB; ++w) M = fmaxf(M, sm_m[w]);
        float L = 0.f, A = 0.f;
        #pragma unroll
        for (int w = 0; w < WPB; ++w) {
            const float f = fexp2(sm_m[w] - M);
            L = fmaf(sm_l[w], f, L);
            A = fmaf(sm_red[w][tid], f, A);
        }
        float* p = part + (i * HALVES + h) * PSTRIDE;
        p[tid] = A;
        if (tid == 0) { p[64] = M; p[65] = L; }
    }
}

// ---------- Kernel 2: merge HALVES partials; fused final MLP + LN + residual --
__global__ __launch_bounds__(64) void k_final(
    const float* __restrict__ hs, const float* __restrict__ part,
    const float* __restrict__ wt_w, const float* __restrict__ wt_b,
    const float* __restrict__ wt_lw, const float* __restrict__ wt_lb,
    float* __restrict__ out)
{
    const int i = blockIdx.x;
    const int tid = threadIdx.x;

    float ms[HALVES], ls[HALVES];
    float M = -INFINITY;
    #pragma unroll
    for (int hh = 0; hh < HALVES; ++hh) {
        const float* p = part + (i * HALVES + hh) * PSTRIDE;
        ms[hh] = p[64]; ls[hh] = p[65];
        M = fmaxf(M, ms[hh]);
    }
    float L = 0.f, A = 0.f;
    #pragma unroll
    for (int hh = 0; hh < HALVES; ++hh) {
        const float f = fexp2(ms[hh] - M);   // M's are in base-2 domain
        L = fmaf(ls[hh], f, L);
        A = fmaf(part[(i * HALVES + hh) * PSTRIDE + tid], f, A);
    }
    const float Hv = A / L;

    float v = wt_b[tid];
    #pragma unroll 8
    for (int k = 0; k < DD; ++k)
        v = fmaf(lane_bcast(Hv, k), wt_w[k * DD + tid], v);
    float t1 = v, t2 = v * v;
    #pragma unroll
    for (int o = 32; o; o >>= 1) { t1 += __shfl_xor(t1, o); t2 += __shfl_xor(t2, o); }
    const float uo = t1 * (1.f / 64.f);
    const float varo = fmaf(t2, 1.f / 64.f, -uo * uo);
    const float invo = rsqrtf(varo + 1e-5f);
    const float ro = fmaf((v - uo) * invo, wt_lw[tid], wt_lb[tid]);
    out[i * DD + tid] = hs[i * DD + tid] + fmaxf(ro, 0.f);
}

extern "C" void kernel_launch(void* const* d_in, const int* in_sizes, int n_in,
                              void* d_out, int out_size, void* d_ws, size_t ws_size,
                              hipStream_t stream) {
    const float* corr   = (const float*)d_in[0];
    const int*   nei    = (const int*)  d_in[1];
    // d_in[2] = nei_num : unused by the reference
    const float* hs     = (const float*)d_in[3];
    const float* av     = (const float*)d_in[4];
    const float* rel_w  = (const float*)d_in[5];
    const float* rel_b  = (const float*)d_in[6];
    const float* rel_lw = (const float*)d_in[7];
    const float* rel_lb = (const float*)d_in[8];
    const float* ng_w   = (const float*)d_in[9];
    const float* ng_b   = (const float*)d_in[10];
    const float* ng_lw  = (const float*)d_in[11];
    const float* ng_lb  = (const float*)d_in[12];
    const float* war_w  = (const float*)d_in[13];
    const float* war_b  = (const float*)d_in[14];
    const float* wt_w   = (const float*)d_in[15];
    const float* wt_b   = (const float*)d_in[16];
    const float* wt_lw  = (const float*)d_in[17];
    const float* wt_lb  = (const float*)d_in[18];
    float* out = (float*)d_out;

    float* ws    = (float*)d_ws;
    float* sbase = ws;                                  // N*D
    float* warb  = sbase + NN * DD;                     // N
    float* war3  = warb + NN;                           // N
    float* mom   = war3 + NN;                           // 14 (+pad to 16)
    unsigned int* hf16   = (unsigned int*)(mom + 16);   // N*32
    unsigned int* afragS = hf16 + NN * 32;              // 16*64*4
    unsigned int* afragR = afragS + 16 * 64 * 4;        // 4*64*4
    float* part  = (float*)(afragR + 4 * 64 * 4);       // N*HALVES*PSTRIDE

    k_prepack<<<PREBLKS + NN / 4, 256, 0, stream>>>(
        hs, ng_w, ng_b, war_w, war_b, rel_w, rel_b, rel_lw, rel_lb,
        sbase, warb, war3, hf16, afragS, afragR, mom);
    k_main<<<dim3(HALVES, NN), 64 * WPB, 0, stream>>>(
        corr, nei, hs, av, ng_lw, ng_lb, war_w, sbase, warb, war3,
        afragS, afragR, hf16, mom, part);
    k_final<<<NN, 64, 0, stream>>>(
        hs, part, wt_w, wt_b, wt_lw, wt_lb, out);
}

// Round 13
// 135.767 us; speedup vs baseline: 1.0601x; 1.0153x over previous
//
#include <hip/hip_runtime.h>
#include <math.h>

#define NN 768
#define DD 64
#define WPB 4                        // waves per block in k_main (256 thr, known-good codegen)
#define HALVES 3                     // j-range split: 3 blocks per row
#define JW (NN / HALVES)             // j per block = 256 -> 64 j per wave
#define NSUB 4                       // 16-j MFMA sub-tiles per wave
#define RSTRIDE 34                   // LDS r-bounce row stride in dwords (pad 2)
#define PREBLKS 18                   // k_prepack: frag/pack blocks before row blocks
#define PSTRIDE 68                   // partial row stride in floats (A[64], M, L, pad)
#define LOG2E 1.4426950408889634f    // all softmax/sigmoid logits carried in base-2 domain
#define WSENT -30000.0f              // masked-j sentinel (|wd+warbase| << 3e4)
#define WTHR  -20000.0f              // mask recovery threshold

typedef _Float16 half8 __attribute__((ext_vector_type(8)));
typedef float    f32x4 __attribute__((ext_vector_type(4)));
typedef __fp16   p2f   __attribute__((ext_vector_type(2)));

union FragU { uint4 u4; unsigned int u[4]; half8 h; };
union PkU   { unsigned int u; p2f p; };

__device__ __forceinline__ unsigned int pk2(float a, float b) {
    PkU t; t.p = __builtin_amdgcn_cvt_pkrtz(a, b); return t.u;
}
__device__ __forceinline__ float lane_bcast(float v, int src) {
    return __int_as_float(__builtin_amdgcn_readlane(__float_as_int(v), src));
}
__device__ __forceinline__ float rfl(float v) {   // force SGPR residency
    return __int_as_float(__builtin_amdgcn_readfirstlane(__float_as_int(v)));
}
__device__ __forceinline__ float fexp2(float x) { // raw v_exp (base-2), no log2e mul
    float r; asm("v_exp_f32 %0, %1" : "=v"(r) : "v"(x)); return r;
}
__device__ __forceinline__ float frcp(float x) {  // raw v_rcp
    float r; asm("v_rcp_f32 %0, %1" : "=v"(r) : "v"(x)); return r;
}
__device__ __forceinline__ f32x4 mfma16(FragU a, FragU b, f32x4 c) {
    return __builtin_amdgcn_mfma_f32_16x16x32_f16(a.h, b.h, c, 0, 0, 0);
}

// ---------- Kernel 0: pack fragments / hf16 / moments (blk<18) + per-row pre (blk>=18)
__global__ __launch_bounds__(256) void k_prepack(
    const float* __restrict__ hs, const float* __restrict__ ng_w,
    const float* __restrict__ ng_b, const float* __restrict__ war_w,
    const float* __restrict__ war_b,
    const float* __restrict__ rel_w, const float* __restrict__ rel_b,
    const float* __restrict__ rel_lw, const float* __restrict__ rel_lb,
    float* __restrict__ sbase, float* __restrict__ warb, float* __restrict__ war3,
    unsigned int* __restrict__ hf16,
    unsigned int* __restrict__ afragS, unsigned int* __restrict__ afragR,
    float* __restrict__ mom)
{
    const int t = threadIdx.x, blk = blockIdx.x;
    const int lane = t & 63, q = t >> 6, g = lane >> 4, c16 = lane & 15;

    if (blk >= PREBLKS) {
        // per-row: sbase = h@W2 + ng_b ; warb/war3 pre-scaled by log2e (softmax
        // runs in base-2 domain; exp2(log2e*x) == exp(x) exactly).
        const int row = (blk - PREBLKS) * 4 + q;
        const float hv = hs[row * DD + lane];
        float a2 = ng_b[lane];
        #pragma unroll 8
        for (int k = 0; k < DD; ++k)
            a2 = fmaf(lane_bcast(hv, k), ng_w[(DD + k) * DD + lane], a2);
        sbase[row * DD + lane] = a2;
        float t2 = hv * war_w[DD + lane];
        float t3 = hv * war_w[2 * DD + lane];
        #pragma unroll
        for (int o = 32; o; o >>= 1) { t2 += __shfl_xor(t2, o); t3 += __shfl_xor(t3, o); }
        if (lane == 0) {
            warb[row] = (t2 + war_b[0]) * LOG2E;
            war3[row] = t3 * LOG2E;
        }
        return;
    }

    // hf16 pack across blocks 0..17
    for (int idx = blk * 256 + t; idx < NN * 32; idx += PREBLKS * 256) {
        const int row = idx >> 5, c = idx & 31;
        hf16[idx] = pk2(hs[row * DD + 2 * c], hs[row * DD + 2 * c + 1]);
    }

    if (blk < 16) {
        // GEMM2 S A-fragments: A[m=dout][k], frag id = b*4+c
        const int b = blk >> 2, c = blk & 3;
        const int dout = 16 * b + c16;
        const int k0 = 32 * c + g * 8 + 2 * q;
        const int r0 = (k0 < 64) ? k0 : (k0 + 64);   // W1 rows 0..63 ; W3 rows 128..191
        afragS[(blk * 64 + lane) * 4 + q] =
            pk2(ng_w[r0 * DD + dout], ng_w[(r0 + 1) * DD + dout]);
    } else if (blk == 16) {
        // GEMM1 A-fragments, split-precision:
        //   k0..5: wh (pairs xh) ; k8..13: wh (pairs xl) ; k16..21: wl (pairs xh)
        const int b = q;                      // m-block
        const int d = 16 * b + c16;
        const float rlwd = rel_lw[d], rlbd = rel_lb[d];
        const float c0 = rel_w[d] * rlwd;
        const float c1 = rel_w[DD + d] * rlwd;
        const float c2 = rel_w[2 * DD + d] * rlwd;
        const float c3 = rel_b[d] * rlwd;
        PkU h01, h23, h45;
        h01.p = __builtin_amdgcn_cvt_pkrtz(c0, c1);
        h23.p = __builtin_amdgcn_cvt_pkrtz(c2, c3);
        h45.p = __builtin_amdgcn_cvt_pkrtz(rlwd, rlbd);
        const unsigned l01 = pk2(c0 - (float)h01.p[0], c1 - (float)h01.p[1]);
        const unsigned l23 = pk2(c2 - (float)h23.p[0], c3 - (float)h23.p[1]);
        const unsigned l45 = pk2(rlwd - (float)h45.p[0], rlbd - (float)h45.p[1]);
        const unsigned int base = (b * 64 + lane) * 4;
        unsigned v0, v1, v2;
        if (g == 0 || g == 1)      { v0 = h01.u; v1 = h23.u; v2 = h45.u; }
        else if (g == 2)           { v0 = l01;   v1 = l23;   v2 = l45;   }
        else                       { v0 = 0u;    v1 = 0u;    v2 = 0u;    }
        afragR[base + 0] = v0;
        afragR[base + 1] = v1;
        afragR[base + 2] = v2;
        afragR[base + 3] = 0u;
    } else { // blk == 17: rel-LN moment matrix
        if (t < 64) {
            const float x0 = rel_w[t], x1 = rel_w[DD + t], x2 = rel_w[2 * DD + t];
            const float x3 = rel_b[t];
            float v[14] = {x0, x1, x2, x3,
                           x0 * x0, x1 * x1, x2 * x2, x3 * x3,
                           x0 * x1, x0 * x2, x0 * x3, x1 * x2, x1 * x3, x2 * x3};
            #pragma unroll
            for (int qq = 0; qq < 14; ++qq) {
                float s = v[qq];
                #pragma unroll
                for (int o = 32; o; o >>= 1) s += __shfl_xor(s, o);
                if (t == 0) mom[qq] = s * (1.f / 64.f);
            }
        }
    }
}

// ---------- Kernel 1: one (row i, j-third h) per block; each wave owns 64 j.
//            Front-end once per j (1 j/lane): angle/rel-LN/pack AND the per-j
//            mask+war3 fold (wfold = msk ? w3 : sentinel), stashed in the
//            unused .w word of the SoA B1 tables -> the sub-tile loop gets it
//            free with the LDS read it already does (removes 8 g-redundant
//            global loads per lane). Partials -> workspace; k_final merges.
__global__ __launch_bounds__(64 * WPB) void k_main(
    const float* __restrict__ corr, const int* __restrict__ nei,
    const float* __restrict__ hs, const float* __restrict__ av,
    const float* __restrict__ ng_lw, const float* __restrict__ ng_lb,
    const float* __restrict__ war_w,
    const float* __restrict__ sbase, const float* __restrict__ warb,
    const float* __restrict__ war3,
    const unsigned int* __restrict__ afragS, const unsigned int* __restrict__ afragR,
    const unsigned int* __restrict__ hf16, const float* __restrict__ mom,
    float* __restrict__ part)
{
    const int h = blockIdx.x;        // 0..HALVES-1
    const int i = blockIdx.y;        // 0..NN-1
    const int tid = threadIdx.x;
    const int lane = tid & 63, wave = tid >> 6;
    const int g = lane >> 4, c16 = lane & 15;

    __shared__ uint4 sm_aS[16 * 64];                 // 16 KB: GEMM2 A-fragments
    __shared__ __align__(16) float sm_cst[4 * DD];   // sb | war16*log2e | lw*log2e | lb*log2e
    __shared__ uint4 sm_b1h[WPB * 64];               // 4 KB: B1 hi words + wfold (SoA)
    __shared__ uint4 sm_b1l[WPB * 64];               // 4 KB: B1 lo words + wfold (SoA)
    __shared__ unsigned int smr[WPB * 16 * RSTRIDE];
    __shared__ float sm_red[WPB][DD];
    __shared__ float sm_m[WPB], sm_l[WPB];

    // ---- stage loop-invariant operands into LDS ----
    for (int f = tid; f < 16 * 64; f += 64 * WPB)
        sm_aS[f] = ((const uint4*)afragS)[f];
    {
        const int a = tid >> 6, d = tid & 63;
        float v;
        if (a == 0)      v = sbase[i * DD + d];
        else if (a == 1) v = war_w[d] * LOG2E;
        else if (a == 2) v = ng_lw[d] * LOG2E;
        else             v = ng_lb[d] * LOG2E;
        sm_cst[a * DD + d] = v;
    }

    // GEMM1 A-fragments stay in registers (small, hot)
    FragU aR[4];
    #pragma unroll
    for (int b = 0; b < 4; ++b) aR[b].u4 = ((const uint4*)afragR)[b * 64 + lane];

    // wave-uniform scalars -> SGPR
    const float m0 = rfl(mom[0]), m1 = rfl(mom[1]), m2 = rfl(mom[2]), m3 = rfl(mom[3]);
    const float M00 = rfl(mom[4]), M11 = rfl(mom[5]), M22 = rfl(mom[6]), M33 = rfl(mom[7]);
    const float M01 = rfl(mom[8]), M02 = rfl(mom[9]), M03 = rfl(mom[10]);
    const float M12 = rfl(mom[11]), M13 = rfl(mom[12]), M23 = rfl(mom[13]);
    const float warbase = rfl(warb[i]);              // already *log2e

    unsigned int* wrbase = smr + (wave * 16 + c16) * RSTRIDE;

    __syncthreads();

    // ---------- front-end: ONE j per lane (no g-redundancy) ----------
    const int jwbase = h * JW + wave * 64;
    {
        const int j = jwbase + lane;
        const float2 cc = ((const float2*)corr)[i * NN + j];
        const float2 vv = ((const float2*)av)[j];
        const int   nvj = nei[i * NN + j];
        const float w3j = war3[j];               // already *log2e
        const float wfold = (nvj > 0) ? w3j : WSENT;

        const float cx = cc.x, cy = cc.y;
        const float judge = vv.x * vv.x + vv.y * vv.y;
        const float dotv = fmaf(vv.x, cx, vv.y * cy);
        const float cn = cx * cx + cy * cy;
        float angle = __fdividef(dotv, sqrtf(judge * cn) + 1e-10f);
        if (judge == 0.f) angle = -1.f;

        // analytic rel-LN stats (quadratic form)
        const float u = fmaf(cx, m0, fmaf(cy, m1, fmaf(angle, m2, m3)));
        float e2 = M33;
        e2 = fmaf(cx * cx, M00, e2);
        e2 = fmaf(cy * cy, M11, e2);
        e2 = fmaf(angle * angle, M22, e2);
        e2 = fmaf(2.f * cx, fmaf(cy, M01, fmaf(angle, M02, M03)), e2);
        e2 = fmaf(2.f * cy, fmaf(angle, M12, M13), e2);
        e2 = fmaf(2.f * angle, M23, e2);
        const float vare = (e2 - u * u) + 1e-5f;
        const float inv = rsqrtf(vare);

        // B operand with inv FOLDED IN: x' = (cx,cy,angle,1,-u,sig)*inv
        // (sig*inv == 1 exactly). Then r = relu(P) directly, no post-scale.
        const float xc0 = cx * inv, xc1 = cy * inv, xc2 = angle * inv;
        const float xc3 = inv, xc4 = -u * inv;
        PkU s01, s23, s45;
        s01.p = __builtin_amdgcn_cvt_pkrtz(xc0, xc1);
        s23.p = __builtin_amdgcn_cvt_pkrtz(xc2, xc3);
        s45.p = __builtin_amdgcn_cvt_pkrtz(xc4, 1.f);
        const unsigned l0 = pk2(xc0 - (float)s01.p[0], xc1 - (float)s01.p[1]);
        const unsigned l1 = pk2(xc2 - (float)s23.p[0], xc3 - (float)s23.p[1]);
        const unsigned l2 = pk2(xc4 - (float)s45.p[0], 0.f);

        const unsigned wfu = __float_as_uint(wfold);
        sm_b1h[wave * 64 + lane] = make_uint4(s01.u, s23.u, s45.u, wfu);
        sm_b1l[wave * 64 + lane] = make_uint4(l0, l1, l2, wfu);
    }

    float acc[16];
    #pragma unroll
    for (int x = 0; x < 16; ++x) acc[x] = 0.f;
    float mrun = -INFINITY, lrun = 0.f;

    unsigned zofs = 0;   // opaque 0: blocks LICM from hoisting LDS reads to regs

    #pragma unroll 1
    for (int s = 0; s < NSUB; ++s) {
        asm volatile("" : "+v"(zofs));
        const uint4* aSp = sm_aS + zofs;
        const float* cst = sm_cst + zofs;

        const int jj = jwbase + 16 * s + c16;
        FragU bx2, bx3;
        bx2.u4 = *(const uint4*)(hf16 + jj * 32 + 4 * g);
        bx3.u4 = *(const uint4*)(hf16 + jj * 32 + 16 + 4 * g);

        // b1 fragment + wfold: SoA tables, 16B stride (conflict-free; broadcasts)
        FragU b1;
        float wfold;
        {
            const int bi = wave * 64 + 16 * s + c16;
            const uint4 w = (g == 1) ? sm_b1l[bi] : sm_b1h[bi];
            b1.u[0] = (g == 3) ? 0u : w.x;
            b1.u[1] = (g == 3) ? 0u : w.y;
            b1.u[2] = (g == 3) ? 0u : w.z;
            b1.u[3] = 0u;
            wfold = __uint_as_float(w.w);
        }

        const f32x4 Z = {0.f, 0.f, 0.f, 0.f};
        // GEMM1 -> r (inv pre-folded); war dot (base-2-scaled) inline; pack to LDS
        float wd = 0.f;
        #pragma unroll
        for (int b = 0; b < 4; ++b) {
            const f32x4 P = mfma16(aR[b], b1, Z);
            const f32x4 wv = *(const f32x4*)(cst + 1 * DD + 16 * b + 4 * g);
            const float r0f = fmaxf(P[0], 0.f);
            const float r1f = fmaxf(P[1], 0.f);
            const float r2f = fmaxf(P[2], 0.f);
            const float r3f = fmaxf(P[3], 0.f);
            wd = fmaf(r0f, wv[0], wd);
            wd = fmaf(r1f, wv[1], wd);
            wd = fmaf(r2f, wv[2], wd);
            wd = fmaf(r3f, wv[3], wd);
            uint2 wvv;
            wvv.x = pk2(r0f, r1f);
            wvv.y = pk2(r2f, r3f);
            *(uint2*)(wrbase + 8 * b + 2 * g) = wvv;   // d2 = 8b+2g, +1
        }

        // issue the LDS reads for GEMM2 chunks 0,1 right behind the writes
        FragU bx0, bx1;
        {
            const uint2 lo0 = *(const uint2*)(wrbase + 4 * g);
            const uint2 hi0 = *(const uint2*)(wrbase + 4 * g + 2);
            bx0.u[0] = lo0.x; bx0.u[1] = lo0.y; bx0.u[2] = hi0.x; bx0.u[3] = hi0.y;
            const uint2 lo1 = *(const uint2*)(wrbase + 16 + 4 * g);
            const uint2 hi1 = *(const uint2*)(wrbase + 16 + 4 * g + 2);
            bx1.u[0] = lo1.x; bx1.u[1] = lo1.y; bx1.u[2] = hi1.x; bx1.u[3] = hi1.y;
        }

        // h_j loads issued mid-sub-tile: consumed at the gate, hidden behind GEMM2+LN
        const f32x4 hv0 = *(const f32x4*)(hs + jj * DD +  0 + 4 * g);
        const f32x4 hv1 = *(const f32x4*)(hs + jj * DD + 16 + 4 * g);
        const f32x4 hv2 = *(const f32x4*)(hs + jj * DD + 32 + 4 * g);
        const f32x4 hv3 = *(const f32x4*)(hs + jj * DD + 48 + 4 * g);

        wd += __shfl_xor(wd, 16);
        wd += __shfl_xor(wd, 32);     // full r@war[0:64] (scaled) for this lane's jj

        // GEMM2: S[dout][j], C-init = sbase (LDS); A-fragments from LDS.
        f32x4 S[4];
        #pragma unroll
        for (int b = 0; b < 4; ++b) {
            f32x4 cinit = *(const f32x4*)(cst + 0 * DD + 16 * b + 4 * g);
            FragU a2f, a3f, a0f, a1f;
            a2f.u4 = aSp[(b * 4 + 2) * 64 + lane];
            a3f.u4 = aSp[(b * 4 + 3) * 64 + lane];
            a0f.u4 = aSp[(b * 4 + 0) * 64 + lane];
            a1f.u4 = aSp[(b * 4 + 1) * 64 + lane];
            cinit = mfma16(a2f, bx2, cinit);
            cinit = mfma16(a3f, bx3, cinit);
            cinit = mfma16(a0f, bx0, cinit);
            cinit = mfma16(a1f, bx1, cinit);
            S[b] = cinit;
        }

        // LayerNorm stats over dout (in-lane 16 + xor16/32)
        float s1 = 0.f, s2 = 0.f;
        #pragma unroll
        for (int x = 0; x < 16; ++x) {
            const float sv = S[x >> 2][x & 3];
            s1 += sv; s2 = fmaf(sv, sv, s2);
        }
        s1 += __shfl_xor(s1, 16); s1 += __shfl_xor(s1, 32);
        s2 += __shfl_xor(s2, 16); s2 += __shfl_xor(s2, 32);
        const float u2 = s1 * (1.f / 64.f);
        const float var2 = fmaf(s2, 1.f / 64.f, -u2 * u2);
        const float inv2 = rsqrtf(var2 + 1e-5f);

        // attention logit (base-2 domain). wfold's sentinel guarantees tt<0
        // for masked j, so the single tt>0 select implements mask && relu.
        const float tt = wd + wfold + warbase;
        const bool msk = wfold > WTHR;
        const float p = (tt > 0.f) ? tt : -10000.f;

        // per-lane online softmax in base-2 (raw v_exp)
        const float mn = fmaxf(mrun, p);
        const float alpha = fexp2(mrun - mn);
        const float e = fexp2(p - mn);
        const float eacc = msk ? e : 0.f;
        lrun = fmaf(lrun, alpha, e);
        mrun = mn;

        // gate + accumulate; LN affine pre-folded AND pre-scaled by log2e:
        // sigmoid(x) = rcp(1 + exp2(-x*log2e)) with the log2e inside ilw/blb.
        #pragma unroll
        for (int b = 0; b < 4; ++b) {
            const f32x4 hvb = (b == 0) ? hv0 : (b == 1) ? hv1 : (b == 2) ? hv2 : hv3;
            const f32x4 lw = *(const f32x4*)(cst + 2 * DD + 16 * b + 4 * g);
            const f32x4 lb = *(const f32x4*)(cst + 3 * DD + 16 * b + 4 * g);
            #pragma unroll
            for (int r = 0; r < 4; ++r) {
                const float ilw = inv2 * lw[r];
                const float blb = fmaf(-u2, ilw, lb[r]);
                const float ngv = fmaf(S[b][r], ilw, blb);
                const float gate = frcp(1.f + fexp2(-ngv));
                const float ehv = eacc * hvb[r];
                acc[b * 4 + r] = fmaf(acc[b * 4 + r], alpha, gate * ehv);
            }
        }
    }

    // softmax-aware merge over the 16 j-classes (bits 0-3); g-duplicates share (m,l)
    #pragma unroll
    for (int o = 1; o <= 8; o <<= 1) {
        const float mo  = __shfl_xor(mrun, o);
        const float lo_ = __shfl_xor(lrun, o);
        const float M   = fmaxf(mrun, mo);
        const float a1  = fexp2(mrun - M);
        const float a2  = fexp2(mo - M);
        lrun = lrun * a1 + lo_ * a2;
        #pragma unroll
        for (int x = 0; x < 16; ++x) {
            const float ao = __shfl_xor(acc[x], o);
            acc[x] = acc[x] * a1 + ao * a2;
        }
        mrun = M;
    }
    if (c16 == 0) {
        #pragma unroll
        for (int b = 0; b < 4; ++b)
            #pragma unroll
            for (int r = 0; r < 4; ++r)
                sm_red[wave][16 * b + g * 4 + r] = acc[b * 4 + r];
        if (lane == 0) { sm_m[wave] = mrun; sm_l[wave] = lrun; }
    }
    __syncthreads();

    // merge the WPB wave partials and emit this third's partial (A, M, L)
    if (tid < DD) {
        float M = sm_m[0];
        #pragma unroll
        for (int w = 1; w < WPB; ++w) M = fmaxf(M, sm_m[w]);
        float L = 0.f, A = 0.f;
        #pragma unroll
        for (int w = 0; w < WPB; ++w) {
            const float f = fexp2(sm_m[w] - M);
            L = fmaf(sm_l[w], f, L);
            A = fmaf(sm_red[w][tid], f, A);
        }
        float* p = part + (i * HALVES + h) * PSTRIDE;
        p[tid] = A;
        if (tid == 0) { p[64] = M; p[65] = L; }
    }
}

// ---------- Kernel 2: merge HALVES partials; fused final MLP + LN + residual --
__global__ __launch_bounds__(64) void k_final(
    const float* __restrict__ hs, const float* __restrict__ part,
    const float* __restrict__ wt_w, const float* __restrict__ wt_b,
    const float* __restrict__ wt_lw, const float* __restrict__ wt_lb,
    float* __restrict__ out)
{
    const int i = blockIdx.x;
    const int tid = threadIdx.x;

    float ms[HALVES], ls[HALVES];
    float M = -INFINITY;
    #pragma unroll
    for (int hh = 0; hh < HALVES; ++hh) {
        const float* p = part + (i * HALVES + hh) * PSTRIDE;
        ms[hh] = p[64]; ls[hh] = p[65];
        M = fmaxf(M, ms[hh]);
    }
    float L = 0.f, A = 0.f;
    #pragma unroll
    for (int hh = 0; hh < HALVES; ++hh) {
        const float f = fexp2(ms[hh] - M);   // M's are in base-2 domain
        L = fmaf(ls[hh], f, L);
        A = fmaf(part[(i * HALVES + hh) * PSTRIDE + tid], f, A);
    }
    const float Hv = A / L;

    float v = wt_b[tid];
    #pragma unroll 8
    for (int k = 0; k < DD; ++k)
        v = fmaf(lane_bcast(Hv, k), wt_w[k * DD + tid], v);
    float t1 = v, t2 = v * v;
    #pragma unroll
    for (int o = 32; o; o >>= 1) { t1 += __shfl_xor(t1, o); t2 += __shfl_xor(t2, o); }
    const float uo = t1 * (1.f / 64.f);
    const float varo = fmaf(t2, 1.f / 64.f, -uo * uo);
    const float invo = rsqrtf(varo + 1e-5f);
    const float ro = fmaf((v - uo) * invo, wt_lw[tid], wt_lb[tid]);
    out[i * DD + tid] = hs[i * DD + tid] + fmaxf(ro, 0.f);
}

extern "C" void kernel_launch(void* const* d_in, const int* in_sizes, int n_in,
                              void* d_out, int out_size, void* d_ws, size_t ws_size,
                              hipStream_t stream) {
    const float* corr   = (const float*)d_in[0];
    const int*   nei    = (const int*)  d_in[1];
    // d_in[2] = nei_num : unused by the reference
    const float* hs     = (const float*)d_in[3];
    const float* av     = (const float*)d_in[4];
    const float* rel_w  = (const float*)d_in[5];
    const float* rel_b  = (const float*)d_in[6];
    const float* rel_lw = (const float*)d_in[7];
    const float* rel_lb = (const float*)d_in[8];
    const float* ng_w   = (const float*)d_in[9];
    const float* ng_b   = (const float*)d_in[10];
    const float* ng_lw  = (const float*)d_in[11];
    const float* ng_lb  = (const float*)d_in[12];
    const float* war_w  = (const float*)d_in[13];
    const float* war_b  = (const float*)d_in[14];
    const float* wt_w   = (const float*)d_in[15];
    const float* wt_b   = (const float*)d_in[16];
    const float* wt_lw  = (const float*)d_in[17];
    const float* wt_lb  = (const float*)d_in[18];
    float* out = (float*)d_out;

    float* ws    = (float*)d_ws;
    float* sbase = ws;                                  // N*D
    float* warb  = sbase + NN * DD;                     // N
    float* war3  = warb + NN;                           // N
    float* mom   = war3 + NN;                           // 14 (+pad to 16)
    unsigned int* hf16   = (unsigned int*)(mom + 16);   // N*32
    unsigned int* afragS = hf16 + NN * 32;              // 16*64*4
    unsigned int* afragR = afragS + 16 * 64 * 4;        // 4*64*4
    float* part  = (float*)(afragR + 4 * 64 * 4);       // N*HALVES*PSTRIDE

    k_prepack<<<PREBLKS + NN / 4, 256, 0, stream>>>(
        hs, ng_w, ng_b, war_w, war_b, rel_w, rel_b, rel_lw, rel_lb,
        sbase, warb, war3, hf16, afragS, afragR, mom);
    k_main<<<dim3(HALVES, NN), 64 * WPB, 0, stream>>>(
        corr, nei, hs, av, ng_lw, ng_lb, war_w, sbase, warb, war3,
        afragS, afragR, hf16, mom, part);
    k_final<<<NN, 64, 0, stream>>>(
        hs, part, wt_w, wt_b, wt_lw, wt_lb, out);
}